// Round 6
// baseline (1240.912 us; speedup 1.0000x reference)
//
#include <hip/hip_runtime.h>
#include <hip/hip_bf16.h>
#include <type_traits>

constexpr int B_ = 8, C_ = 256, P_ = 64, H_ = 64, W_ = 64, HW_ = 4096;

typedef __attribute__((ext_vector_type(8))) short short8;   // 8 bf16
typedef __attribute__((ext_vector_type(4))) short short4v;  // 4 bf16 (8 B)
typedef __attribute__((ext_vector_type(4))) float f32x4;

__device__ __forceinline__ short bfbits(float f) {
    __hip_bfloat16 h = __float2bfloat16(f);
    return *reinterpret_cast<short*>(&h);
}
__device__ __forceinline__ float bf2f(short s) {
    __hip_bfloat16 h = *reinterpret_cast<__hip_bfloat16*>(&s);
    return (float)h;
}

// ---------------------------------------------------------------------------
// K0: weight prep. w fp32 [co][ci][3][3] (OIHW) -> wb bf16 [tap][co][ci].
// ---------------------------------------------------------------------------
__global__ __launch_bounds__(256) void k_prep_w(
    const float* __restrict__ w, __hip_bfloat16* __restrict__ wb)
{
    const int i = blockIdx.x * 256 + threadIdx.x;        // over 9*256*256
    const int tap = i >> 16;
    const int co  = (i >> 8) & 255;
    const int ci  = i & 255;
    wb[i] = __float2bfloat16(w[(co * 256 + ci) * 9 + tap]);
}

// ---------------------------------------------------------------------------
// K1: 1x1 convs, p-quarter split for occupancy (grid 16x8x8 = 1024 blocks).
// ---------------------------------------------------------------------------
__global__ __launch_bounds__(256) void k_conv1x1(
    const float* __restrict__ x,
    const float* __restrict__ w_top, const float* __restrict__ b_top,
    const float* __restrict__ w_cen, const float* __restrict__ b_cen,
    __hip_bfloat16* __restrict__ xtTh, __hip_bfloat16* __restrict__ xtTl,
    __hip_bfloat16* __restrict__ xcTh, __hip_bfloat16* __restrict__ xcTl)
{
    const int b = blockIdx.z;
    const int n = blockIdx.x * 256 + threadIdx.x;
    const int conv = blockIdx.y >> 2, pq = blockIdx.y & 3;
    const int p0 = pq * 16;
    const float* w    = conv ? w_cen : w_top;
    const float* bias = conv ? b_cen : b_top;
    __hip_bfloat16* oh = conv ? xcTh : xtTh;
    __hip_bfloat16* ol = conv ? xcTl : xtTl;

    const float* xp = x + (size_t)b * C_ * HW_ + n;
    float acc[16];
#pragma unroll
    for (int p = 0; p < 16; ++p) acc[p] = 0.f;

    for (int c = 0; c < C_; c += 4) {
        const float xv0 = xp[(size_t)(c + 0) * HW_];
        const float xv1 = xp[(size_t)(c + 1) * HW_];
        const float xv2 = xp[(size_t)(c + 2) * HW_];
        const float xv3 = xp[(size_t)(c + 3) * HW_];
#pragma unroll
        for (int p = 0; p < 16; ++p) {
            const float4 wv = *reinterpret_cast<const float4*>(&w[(p0 + p) * C_ + c]);
            float a = acc[p];
            a = fmaf(wv.x, xv0, a);
            a = fmaf(wv.y, xv1, a);
            a = fmaf(wv.z, xv2, a);
            a = fmaf(wv.w, xv3, a);
            acc[p] = a;
        }
    }
    const size_t rbase = ((size_t)b * HW_ + n) * P_ + p0;
#pragma unroll
    for (int j = 0; j < 2; ++j) {
        short8 vh, vl;
#pragma unroll
        for (int k = 0; k < 8; ++k) {
            const float v = acc[j * 8 + k] + bias[p0 + j * 8 + k];
            const short hb = bfbits(v);
            vh[k] = hb;
            vl[k] = bfbits(v - bf2f(hb));   // residual for hi/lo split
        }
        *reinterpret_cast<short8*>(&oh[rbase + j * 8]) = vh;
        *reinterpret_cast<short8*>(&ol[rbase + j * 8]) = vl;
    }
}

// ---------------------------------------------------------------------------
// K2/K5: 3x3 conv as implicit GEMM, bf16 MFMA. co-half split for occupancy:
// grid (h=64, cohalf=2, b=8) = 1024 blocks; wave owns 32 co (2 co-tiles).
// ---------------------------------------------------------------------------
template <typename OT>
__global__ __launch_bounds__(256) void k_conv3x3_mfma(
    const float* __restrict__ xin, const __hip_bfloat16* __restrict__ wb,
    const float* __restrict__ bias, OT* __restrict__ out)
{
    __shared__ __align__(16) __hip_bfloat16 Xs[3][66][40];
    const int b = blockIdx.z, h = blockIdx.x, cohalf = blockIdx.y;
    const int t = threadIdx.x;
    const int wave = t >> 6, lane = t & 63;
    const int lm = lane & 15, lq = lane >> 4;
    const int cobase = cohalf * 128 + wave * 32;

    f32x4 acc[4][2];   // [n_tile][co_tile]
#pragma unroll
    for (int i = 0; i < 4; ++i)
#pragma unroll
        for (int j = 0; j < 2; ++j) acc[i][j] = f32x4{0.f, 0.f, 0.f, 0.f};

    if (t < 192) {   // zero w-halo columns once
        const int r = t >> 6, cc = t & 31, side = (t >> 5) & 1;
        Xs[r][side ? 65 : 0][cc] = __float2bfloat16(0.f);
    }

    const int ci_ld = t & 31;
    const int grp   = t >> 5;
    const float* xbase = xin + (size_t)b * C_ * HW_;

    for (int cb = 0; cb < 8; ++cb) {
        const int ci0 = cb * 32;
        __syncthreads();
#pragma unroll
        for (int it = 0; it < 6; ++it) {
            const int qr = it * 8 + grp;
            const int r = qr >> 4, wq = qr & 15;
            const int hh = h + r - 1;
            float4 v = {0.f, 0.f, 0.f, 0.f};
            if (hh >= 0 && hh < H_)
                v = *reinterpret_cast<const float4*>(
                    &xbase[(size_t)(ci0 + ci_ld) * HW_ + hh * W_ + wq * 4]);
            Xs[r][1 + wq * 4 + 0][ci_ld] = __float2bfloat16(v.x);
            Xs[r][1 + wq * 4 + 1][ci_ld] = __float2bfloat16(v.y);
            Xs[r][1 + wq * 4 + 2][ci_ld] = __float2bfloat16(v.z);
            Xs[r][1 + wq * 4 + 3][ci_ld] = __float2bfloat16(v.w);
        }
        __syncthreads();

        for (int tap = 0; tap < 9; ++tap) {
            const int dh = tap / 3;
            const int dw = tap % 3;
            short8 bf[4];
#pragma unroll
            for (int nt = 0; nt < 4; ++nt)
                bf[nt] = *reinterpret_cast<const short8*>(
                    &Xs[dh][nt * 16 + lm + dw][lq * 8]);
            short8 af[2];
            const __hip_bfloat16* wt = wb + ((size_t)tap * C_) * C_ + ci0 + lq * 8;
#pragma unroll
            for (int ct = 0; ct < 2; ++ct) {
                const int co = cobase + ct * 16 + lm;
                af[ct] = *reinterpret_cast<const short8*>(&wt[(size_t)co * C_]);
            }
#pragma unroll
            for (int nt = 0; nt < 4; ++nt)
#pragma unroll
                for (int ct = 0; ct < 2; ++ct)
                    acc[nt][ct] = __builtin_amdgcn_mfma_f32_16x16x32_bf16(
                        af[ct], bf[nt], acc[nt][ct], 0, 0, 0);
        }
    }

    // Epilogue [B][C][HW]. C/D: col(n)=lane&15, row(co)=lq*4+reg.
#pragma unroll
    for (int nt = 0; nt < 4; ++nt) {
        const int pos = h * W_ + nt * 16 + lm;
#pragma unroll
        for (int ct = 0; ct < 2; ++ct) {
            const int co = cobase + ct * 16 + lq * 4;
#pragma unroll
            for (int r = 0; r < 4; ++r) {
                const float v = acc[nt][ct][r] + bias[co + r];
                if constexpr (std::is_same<OT, __hip_bfloat16>::value)
                    out[((size_t)(b * C_ + co + r)) * HW_ + pos] = __float2bfloat16(v);
                else
                    out[((size_t)(b * C_ + co + r)) * HW_ + pos] = v;
            }
        }
    }
}

// ---------------------------------------------------------------------------
// K3: fused attention, all-MFMA, barrier-free, c-SPLIT for register-file
// occupancy: block = 64n x 128c-half, wave = 16n x 128c -> acc 32 AGPRs,
// arch VGPR capped by __launch_bounds__(256,4) to total <=128 -> 16 waves/CU.
// Grid 64x2x8 = 1024 = exactly 4 resident blocks/CU. S recomputed per c-half
// (extra S MFMAs, L1-hot xt loads); Z added by ch==0 blocks only.
// ---------------------------------------------------------------------------
__global__ __launch_bounds__(256, 4) void k_attn_mfma(
    const __hip_bfloat16* __restrict__ xtTh, const __hip_bfloat16* __restrict__ xtTl,
    const __hip_bfloat16* __restrict__ xcTh, const __hip_bfloat16* __restrict__ xcTl,
    const __hip_bfloat16* __restrict__ xb, float* __restrict__ O,
    float* __restrict__ Z)
{
    __shared__ __align__(16) short Ps[4][16][72];   // per-wave P[n16][m64]
    __shared__ float zred[4];
    const int b = blockIdx.z, n0 = blockIdx.x * 64, ch = blockIdx.y;
    const int t = threadIdx.x, wv = t >> 6, lane = t & 63;
    const int lm = lane & 15, lq = lane >> 4;
    const int nrow = n0 + wv * 16;   // this wave's n-stripe base
    const int cbase = ch * 128;      // this block's c-half base

    // Hoisted S^T B-frags: xc cols n (wave's own 16 rows). [kc][hi/lo]
    short8 cB[2][2];
    {
        const size_t r = ((size_t)b * HW_ + nrow + lm) * P_ + lq * 8;
#pragma unroll
        for (int kc = 0; kc < 2; ++kc) {
            cB[kc][0] = *reinterpret_cast<const short8*>(&xcTh[r + kc * 32]);
            cB[kc][1] = *reinterpret_cast<const short8*>(&xcTl[r + kc * 32]);
        }
    }

    f32x4 acc[8];   // O[own n-stripe][128 c-half]: 8 c-tiles
#pragma unroll
    for (int i = 0; i < 8; ++i) acc[i] = f32x4{0.f, 0.f, 0.f, 0.f};
    float zp = 0.f;

    for (int mt = 0; mt < 64; ++mt) {
        const int m0 = mt * 64;
        // S^T over 4 m-subtiles: A = xt rows m (L1/L2-hot, shared across waves)
#pragma unroll
        for (int ms = 0; ms < 4; ++ms) {
            const size_t ar = ((size_t)b * HW_ + m0 + ms * 16 + lm) * P_ + lq * 8;
            const short8 aH0 = *reinterpret_cast<const short8*>(&xtTh[ar]);
            const short8 aH1 = *reinterpret_cast<const short8*>(&xtTh[ar + 32]);
            const short8 aL0 = *reinterpret_cast<const short8*>(&xtTl[ar]);
            const short8 aL1 = *reinterpret_cast<const short8*>(&xtTl[ar + 32]);
            f32x4 s = {0.f, 0.f, 0.f, 0.f};
            s = __builtin_amdgcn_mfma_f32_16x16x32_bf16(aH0, cB[0][0], s, 0, 0, 0);
            s = __builtin_amdgcn_mfma_f32_16x16x32_bf16(aH1, cB[1][0], s, 0, 0, 0);
            s = __builtin_amdgcn_mfma_f32_16x16x32_bf16(aH0, cB[0][1], s, 0, 0, 0);
            s = __builtin_amdgcn_mfma_f32_16x16x32_bf16(aH1, cB[1][1], s, 0, 0, 0);
            s = __builtin_amdgcn_mfma_f32_16x16x32_bf16(aL0, cB[0][0], s, 0, 0, 0);
            s = __builtin_amdgcn_mfma_f32_16x16x32_bf16(aL1, cB[1][0], s, 0, 0, 0);
            // exp + pack into own LDS region: n = lm, m = ms*16 + lq*4 + r
            const float e0 = __expf(s[0]), e1 = __expf(s[1]);
            const float e2 = __expf(s[2]), e3 = __expf(s[3]);
            zp += (e0 + e1) + (e2 + e3);
            short4v pk = { bfbits(e0), bfbits(e1), bfbits(e2), bfbits(e3) };
            *reinterpret_cast<short4v*>(&Ps[wv][lm][ms * 16 + lq * 4]) = pk;
        }
        // PV A-frags from own region (same-wave order via lgkmcnt; no barrier)
        const short8 pa0 = *reinterpret_cast<const short8*>(&Ps[wv][lm][lq * 8]);
        const short8 pa1 = *reinterpret_cast<const short8*>(&Ps[wv][lm][32 + lq * 8]);
        // PV: B = xb[c][m] direct from global (natural conv layout, L1/L2-hot)
        const size_t xbb = ((size_t)(b * C_ + cbase)) * HW_ + m0 + lq * 8;
#pragma unroll
        for (int ct = 0; ct < 8; ++ct) {
            const size_t cr = xbb + (size_t)(ct * 16 + lm) * HW_;
            const short8 b0 = *reinterpret_cast<const short8*>(&xb[cr]);
            const short8 b1 = *reinterpret_cast<const short8*>(&xb[cr + 32]);
            acc[ct] = __builtin_amdgcn_mfma_f32_16x16x32_bf16(pa0, b0, acc[ct], 0, 0, 0);
            acc[ct] = __builtin_amdgcn_mfma_f32_16x16x32_bf16(pa1, b1, acc[ct], 0, 0, 0);
        }
    }

    // Z: block reduction -> one atomicAdd (only ch==0; avoids double count)
#pragma unroll
    for (int o = 32; o > 0; o >>= 1) zp += __shfl_down(zp, o, 64);
    if (lane == 0) zred[wv] = zp;
    __syncthreads();
    if (t == 0 && ch == 0)
        atomicAdd(&Z[b], (zred[0] + zred[1]) + (zred[2] + zred[3]));

    // O stores (coalesced along c, 64 B segments)
#pragma unroll
    for (int ct = 0; ct < 8; ++ct) {
        const int c = cbase + ct * 16 + lm;
#pragma unroll
        for (int r = 0; r < 4; ++r) {
            const int n = nrow + lq * 4 + r;
            O[((size_t)b * HW_ + n) * C_ + c] = acc[ct][r];
        }
    }
}

// ---------------------------------------------------------------------------
// K4: y = x + O*(1/Z[b]) (flat reinterpretation add).
// ---------------------------------------------------------------------------
__global__ __launch_bounds__(256) void k_add(
    const float* __restrict__ x, const float* __restrict__ o,
    const float* __restrict__ Z, float* __restrict__ y)
{
    const int bidx = blockIdx.x;
    const float invZ = 1.0f / Z[bidx >> 10];
    const size_t i = ((size_t)bidx * 256 + threadIdx.x) * 4;
    const float4 a = *reinterpret_cast<const float4*>(&x[i]);
    const float4 b = *reinterpret_cast<const float4*>(&o[i]);
    float4 r{fmaf(b.x, invZ, a.x), fmaf(b.y, invZ, a.y),
             fmaf(b.z, invZ, a.z), fmaf(b.w, invZ, a.w)};
    *reinterpret_cast<float4*>(&y[i]) = r;
}

extern "C" void kernel_launch(void* const* d_in, const int* in_sizes, int n_in,
                              void* d_out, int out_size, void* d_ws, size_t ws_size,
                              hipStream_t stream)
{
    const float* x   = (const float*)d_in[0];
    const float* wt  = (const float*)d_in[1];
    const float* bt  = (const float*)d_in[2];
    const float* wc  = (const float*)d_in[3];
    const float* bc  = (const float*)d_in[4];
    const float* wbo = (const float*)d_in[5];
    const float* bbo = (const float*)d_in[6];
    const float* wo  = (const float*)d_in[7];
    const float* bo  = (const float*)d_in[8];
    float* out = (float*)d_out;

    uint8_t* w8 = (uint8_t*)d_ws;
    const size_t MB = 1u << 20;
    // Phase 1 (until k_attn done): [0,32MB) = xtT/xcT hi/lo + xb bf16
    __hip_bfloat16* xtTh = (__hip_bfloat16*)(w8);            //  4 MB
    __hip_bfloat16* xtTl = (__hip_bfloat16*)(w8 + 4 * MB);   //  4 MB
    __hip_bfloat16* xcTh = (__hip_bfloat16*)(w8 + 8 * MB);   //  4 MB
    __hip_bfloat16* xcTl = (__hip_bfloat16*)(w8 + 12 * MB);  //  4 MB
    __hip_bfloat16* xbB  = (__hip_bfloat16*)(w8 + 16 * MB);  // 16 MB
    // Phase 2: y reuses [0,32MB)
    float* y = (float*)(w8);                                 // 32 MB
    float* O = (float*)(w8 + 32 * MB);                       // 32 MB
    __hip_bfloat16* Wb1 = (__hip_bfloat16*)(w8 + 32 * MB);   // in O region (dead before attn writes O)
    __hip_bfloat16* Wb2 = (__hip_bfloat16*)(w8 + 64 * MB);   // 1.2 MB
    float* Z = (float*)(w8 + 66 * MB);

    hipMemsetAsync(Z, 0, B_ * sizeof(float), stream);
    k_prep_w<<<dim3(2304), 256, 0, stream>>>(wbo, Wb1);
    k_conv1x1<<<dim3(16, 8, 8), 256, 0, stream>>>(x, wt, bt, wc, bc,
                                                  xtTh, xtTl, xcTh, xcTl);
    k_conv3x3_mfma<__hip_bfloat16><<<dim3(64, 2, 8), 256, 0, stream>>>(x, Wb1, bbo, xbB);
    k_attn_mfma<<<dim3(64, 2, 8), 256, 0, stream>>>(xtTh, xtTl, xcTh, xcTl, xbB, O, Z);
    k_prep_w<<<dim3(2304), 256, 0, stream>>>(wo, Wb2);
    k_add<<<dim3(8192), 256, 0, stream>>>(x, O, Z, y);
    k_conv3x3_mfma<float><<<dim3(64, 2, 8), 256, 0, stream>>>(y, Wb2, bo, out);
}

// Round 7
// 983.533 us; speedup vs baseline: 1.2617x; 1.2617x over previous
//
#include <hip/hip_runtime.h>
#include <hip/hip_bf16.h>
#include <type_traits>

constexpr int B_ = 8, C_ = 256, P_ = 64, H_ = 64, W_ = 64, HW_ = 4096;

typedef __attribute__((ext_vector_type(8))) short short8;   // 8 bf16
typedef __attribute__((ext_vector_type(4))) short short4v;  // 4 bf16 (8 B)
typedef __attribute__((ext_vector_type(4))) float f32x4;

__device__ __forceinline__ short bfbits(float f) {
    __hip_bfloat16 h = __float2bfloat16(f);
    return *reinterpret_cast<short*>(&h);
}
__device__ __forceinline__ float bf2f(short s) {
    __hip_bfloat16 h = *reinterpret_cast<__hip_bfloat16*>(&s);
    return (float)h;
}

// ---------------------------------------------------------------------------
// Fragment-linear packed layouts (one wave-load = base + lane*16, contiguous):
//   xtP/xcP [b][tile16][kc2][lane64]x16B : chunk = x[row=tile*16+lm][p=kc*32+lq*8..+8]
//   xbP     [b][g128][ct16][lane64]x16B  : chunk = xb[c=ct*16+lm][m=g*32+lq*8..+8]
//   wbP     [tap9][cb8][cot16][lane64]x16B: chunk = w[co=cot*16+lm][ci=cb*32+lq*8..+8]
// ---------------------------------------------------------------------------

// K0: weight prep, fp32 OIHW -> fragment-linear bf16 wbP. 288 blocks.
__global__ __launch_bounds__(256) void k_prep_w(
    const float* __restrict__ w, short8* __restrict__ wbP)
{
    const int idx = blockIdx.x * 256 + threadIdx.x;      // < 9*8*16*64 = 73728
    const int lane = idx & 63, cot = (idx >> 6) & 15;
    const int cb = (idx >> 10) & 7, tap = idx >> 13;
    const int lm = lane & 15, lq = lane >> 4;
    const int co = cot * 16 + lm, ci0 = cb * 32 + lq * 8;
    short8 v;
#pragma unroll
    for (int k = 0; k < 8; ++k)
        v[k] = bfbits(w[(co * 256 + ci0 + k) * 9 + tap]);
    wbP[idx] = v;
}

// K0b: xb [B][C][HW] bf16 -> fragment-linear xbP. 4096 blocks.
// Wave handles one (b,g,ct): reads 16 c-rows x 64 B, writes 1 KB contiguous.
__global__ __launch_bounds__(256) void k_pack_xb(
    const __hip_bfloat16* __restrict__ xb, short8* __restrict__ xbP)
{
    const int tid = blockIdx.x * 256 + threadIdx.x;
    const int lane = tid & 63, wid = tid >> 6;           // wid < 8*128*16
    const int ct = wid & 15, g = (wid >> 4) & 127, b = wid >> 11;
    const int c = ct * 16 + (lane >> 2);
    const int mo = g * 32 + (lane & 3) * 8;
    const short8 v = *reinterpret_cast<const short8*>(
        &xb[((size_t)(b * 256 + c)) * HW_ + mo]);
    xbP[(size_t)wid * 64 + (lane & 3) * 16 + (lane >> 2)] = v;
}

// ---------------------------------------------------------------------------
// K1: 1x1 convs, p-quarter split (grid 16x8x8). Epilogue writes hi/lo bf16
// directly in fragment-linear xtP/xcP order (address change only vs R6).
// ---------------------------------------------------------------------------
__global__ __launch_bounds__(256) void k_conv1x1(
    const float* __restrict__ x,
    const float* __restrict__ w_top, const float* __restrict__ b_top,
    const float* __restrict__ w_cen, const float* __restrict__ b_cen,
    short8* __restrict__ xtPh, short8* __restrict__ xtPl,
    short8* __restrict__ xcPh, short8* __restrict__ xcPl)
{
    const int b = blockIdx.z;
    const int n = blockIdx.x * 256 + threadIdx.x;
    const int conv = blockIdx.y >> 2, pq = blockIdx.y & 3;
    const int p0 = pq * 16;
    const float* w    = conv ? w_cen : w_top;
    const float* bias = conv ? b_cen : b_top;
    short8* oh = conv ? xcPh : xtPh;
    short8* ol = conv ? xcPl : xtPl;

    const float* xp = x + (size_t)b * C_ * HW_ + n;
    float acc[16];
#pragma unroll
    for (int p = 0; p < 16; ++p) acc[p] = 0.f;

    for (int c = 0; c < C_; c += 4) {
        const float xv0 = xp[(size_t)(c + 0) * HW_];
        const float xv1 = xp[(size_t)(c + 1) * HW_];
        const float xv2 = xp[(size_t)(c + 2) * HW_];
        const float xv3 = xp[(size_t)(c + 3) * HW_];
#pragma unroll
        for (int p = 0; p < 16; ++p) {
            const float4 wv = *reinterpret_cast<const float4*>(&w[(p0 + p) * C_ + c]);
            float a = acc[p];
            a = fmaf(wv.x, xv0, a);
            a = fmaf(wv.y, xv1, a);
            a = fmaf(wv.z, xv2, a);
            a = fmaf(wv.w, xv3, a);
            acc[p] = a;
        }
    }
    // packed write: tile = n>>4, lm = n&15, kc = pq>>1, lq = (pq&1)*2 + jj
    const int nt = n >> 4, lmn = n & 15;
    const size_t obase = ((size_t)(b * 256 + nt) * 2 + (pq >> 1)) * 64 + lmn;
#pragma unroll
    for (int jj = 0; jj < 2; ++jj) {
        short8 vh, vl;
#pragma unroll
        for (int k = 0; k < 8; ++k) {
            const float v = acc[jj * 8 + k] + bias[p0 + jj * 8 + k];
            const short hb = bfbits(v);
            vh[k] = hb;
            vl[k] = bfbits(v - bf2f(hb));   // residual for hi/lo split
        }
        const size_t idx = obase + (size_t)(((pq & 1) * 2 + jj) * 16);
        oh[idx] = vh;
        ol[idx] = vl;
    }
}

// ---------------------------------------------------------------------------
// K2/K5: 3x3 conv as implicit GEMM, bf16 MFMA, co-half split (grid 64x2x8).
// Weights from fragment-linear wbP (contiguous 1 KB wave-loads).
// ---------------------------------------------------------------------------
template <typename OT>
__global__ __launch_bounds__(256) void k_conv3x3_mfma(
    const float* __restrict__ xin, const short8* __restrict__ wbP,
    const float* __restrict__ bias, OT* __restrict__ out)
{
    __shared__ __align__(16) __hip_bfloat16 Xs[3][66][40];
    const int b = blockIdx.z, h = blockIdx.x, cohalf = blockIdx.y;
    const int t = threadIdx.x;
    const int wave = t >> 6, lane = t & 63;
    const int lm = lane & 15, lq = lane >> 4;
    const int cobase = cohalf * 128 + wave * 32;
    const int cot0 = cohalf * 8 + wave * 2;   // co-tile index base (co/16)

    f32x4 acc[4][2];   // [n_tile][co_tile]
#pragma unroll
    for (int i = 0; i < 4; ++i)
#pragma unroll
        for (int j = 0; j < 2; ++j) acc[i][j] = f32x4{0.f, 0.f, 0.f, 0.f};

    if (t < 192) {   // zero w-halo columns once
        const int r = t >> 6, cc = t & 31, side = (t >> 5) & 1;
        Xs[r][side ? 65 : 0][cc] = __float2bfloat16(0.f);
    }

    const int ci_ld = t & 31;
    const int grp   = t >> 5;
    const float* xbase = xin + (size_t)b * C_ * HW_;

    for (int cb = 0; cb < 8; ++cb) {
        const int ci0 = cb * 32;
        __syncthreads();
#pragma unroll
        for (int it = 0; it < 6; ++it) {
            const int qr = it * 8 + grp;
            const int r = qr >> 4, wq = qr & 15;
            const int hh = h + r - 1;
            float4 v = {0.f, 0.f, 0.f, 0.f};
            if (hh >= 0 && hh < H_)
                v = *reinterpret_cast<const float4*>(
                    &xbase[(size_t)(ci0 + ci_ld) * HW_ + hh * W_ + wq * 4]);
            Xs[r][1 + wq * 4 + 0][ci_ld] = __float2bfloat16(v.x);
            Xs[r][1 + wq * 4 + 1][ci_ld] = __float2bfloat16(v.y);
            Xs[r][1 + wq * 4 + 2][ci_ld] = __float2bfloat16(v.z);
            Xs[r][1 + wq * 4 + 3][ci_ld] = __float2bfloat16(v.w);
        }
        __syncthreads();

        for (int tap = 0; tap < 9; ++tap) {
            const int dh = tap / 3;
            const int dw = tap % 3;
            short8 bf[4];
#pragma unroll
            for (int nt = 0; nt < 4; ++nt)
                bf[nt] = *reinterpret_cast<const short8*>(
                    &Xs[dh][nt * 16 + lm + dw][lq * 8]);
            const short8* wp = wbP + ((size_t)(tap * 8 + cb)) * 1024 + lane;
            short8 af[2];
            af[0] = wp[(cot0 + 0) * 64];
            af[1] = wp[(cot0 + 1) * 64];
#pragma unroll
            for (int nt = 0; nt < 4; ++nt)
#pragma unroll
                for (int ct = 0; ct < 2; ++ct)
                    acc[nt][ct] = __builtin_amdgcn_mfma_f32_16x16x32_bf16(
                        af[ct], bf[nt], acc[nt][ct], 0, 0, 0);
        }
    }

    // Epilogue [B][C][HW]. C/D: col(n)=lane&15, row(co)=lq*4+reg.
#pragma unroll
    for (int nt = 0; nt < 4; ++nt) {
        const int pos = h * W_ + nt * 16 + lm;
#pragma unroll
        for (int ct = 0; ct < 2; ++ct) {
            const int co = cobase + ct * 16 + lq * 4;
#pragma unroll
            for (int r = 0; r < 4; ++r) {
                const float v = acc[nt][ct][r] + bias[co + r];
                if constexpr (std::is_same<OT, __hip_bfloat16>::value)
                    out[((size_t)(b * C_ + co + r)) * HW_ + pos] = __float2bfloat16(v);
                else
                    out[((size_t)(b * C_ + co + r)) * HW_ + pos] = v;
            }
        }
    }
}

// ---------------------------------------------------------------------------
// K3: fused attention, all-MFMA, barrier-free (R4 structure), ALL operand
// loads fragment-linear contiguous (base + lane*16). Wave owns 16n x 256c
// over all 64 m-tiles; private per-wave P in LDS (same-wave lgkmcnt order).
// ---------------------------------------------------------------------------
__global__ __launch_bounds__(256, 2) void k_attn_mfma(
    const short8* __restrict__ xtPh, const short8* __restrict__ xtPl,
    const short8* __restrict__ xcPh, const short8* __restrict__ xcPl,
    const short8* __restrict__ xbP, float* __restrict__ O,
    float* __restrict__ Z)
{
    __shared__ __align__(16) short Ps[4][16][72];   // per-wave P[n16][m64]
    __shared__ float zred[4];
    const int b = blockIdx.y, n0 = blockIdx.x * 64;
    const int t = threadIdx.x, wv = t >> 6, lane = t & 63;
    const int lm = lane & 15, lq = lane >> 4;
    const int nrow = n0 + wv * 16;

    // Hoisted S^T B-frags (xc, wave's own n-tile), contiguous loads
    short8 cB[2][2];
    {
        const size_t c8 = ((size_t)(b * 256 + (n0 >> 4) + wv) * 2) * 64 + lane;
        cB[0][0] = xcPh[c8];      cB[1][0] = xcPh[c8 + 64];
        cB[0][1] = xcPl[c8];      cB[1][1] = xcPl[c8 + 64];
    }

    f32x4 acc[16];   // O[own n-stripe][256 c]
#pragma unroll
    for (int i = 0; i < 16; ++i) acc[i] = f32x4{0.f, 0.f, 0.f, 0.f};
    float zp = 0.f;

    for (int mt = 0; mt < 64; ++mt) {
        // S^T over 4 m-subtiles; A = xt (contiguous fragment-linear loads)
#pragma unroll
        for (int ms = 0; ms < 4; ++ms) {
            const size_t a8 = ((size_t)(b * 256 + mt * 4 + ms) * 2) * 64 + lane;
            const short8 aH0 = xtPh[a8];
            const short8 aH1 = xtPh[a8 + 64];
            const short8 aL0 = xtPl[a8];
            const short8 aL1 = xtPl[a8 + 64];
            f32x4 s = {0.f, 0.f, 0.f, 0.f};
            s = __builtin_amdgcn_mfma_f32_16x16x32_bf16(aH0, cB[0][0], s, 0, 0, 0);
            s = __builtin_amdgcn_mfma_f32_16x16x32_bf16(aH1, cB[1][0], s, 0, 0, 0);
            s = __builtin_amdgcn_mfma_f32_16x16x32_bf16(aH0, cB[0][1], s, 0, 0, 0);
            s = __builtin_amdgcn_mfma_f32_16x16x32_bf16(aH1, cB[1][1], s, 0, 0, 0);
            s = __builtin_amdgcn_mfma_f32_16x16x32_bf16(aL0, cB[0][0], s, 0, 0, 0);
            s = __builtin_amdgcn_mfma_f32_16x16x32_bf16(aL1, cB[1][0], s, 0, 0, 0);
            // exp + pack into own LDS region: n = lm, m = ms*16 + lq*4 + r
            const float e0 = __expf(s[0]), e1 = __expf(s[1]);
            const float e2 = __expf(s[2]), e3 = __expf(s[3]);
            zp += (e0 + e1) + (e2 + e3);
            short4v pk = { bfbits(e0), bfbits(e1), bfbits(e2), bfbits(e3) };
            *reinterpret_cast<short4v*>(&Ps[wv][lm][ms * 16 + lq * 4]) = pk;
        }
        // PV A-frags from own LDS region (same-wave lgkmcnt; no barrier)
        const short8 pa0 = *reinterpret_cast<const short8*>(&Ps[wv][lm][lq * 8]);
        const short8 pa1 = *reinterpret_cast<const short8*>(&Ps[wv][lm][32 + lq * 8]);
        // PV B-frags: contiguous fragment-linear xbP loads
        const size_t p8 = ((size_t)(b * 128 + mt * 2) * 16) * 64 + lane;
#pragma unroll
        for (int ct = 0; ct < 16; ++ct) {
            const short8 b0 = xbP[p8 + ct * 64];
            const short8 b1 = xbP[p8 + 1024 + ct * 64];
            acc[ct] = __builtin_amdgcn_mfma_f32_16x16x32_bf16(pa0, b0, acc[ct], 0, 0, 0);
            acc[ct] = __builtin_amdgcn_mfma_f32_16x16x32_bf16(pa1, b1, acc[ct], 0, 0, 0);
        }
    }

    // Z: block reduction -> one atomicAdd (sole barrier in the kernel)
#pragma unroll
    for (int o = 32; o > 0; o >>= 1) zp += __shfl_down(zp, o, 64);
    if (lane == 0) zred[wv] = zp;
    __syncthreads();
    if (t == 0) atomicAdd(&Z[b], (zred[0] + zred[1]) + (zred[2] + zred[3]));

    // O stores (coalesced along c, 64 B segments)
#pragma unroll
    for (int ct = 0; ct < 16; ++ct) {
        const int c = ct * 16 + lm;
#pragma unroll
        for (int r = 0; r < 4; ++r) {
            const int n = nrow + lq * 4 + r;
            O[((size_t)b * HW_ + n) * C_ + c] = acc[ct][r];
        }
    }
}

// ---------------------------------------------------------------------------
// K4: y = x + O*(1/Z[b]) (flat reinterpretation add).
// ---------------------------------------------------------------------------
__global__ __launch_bounds__(256) void k_add(
    const float* __restrict__ x, const float* __restrict__ o,
    const float* __restrict__ Z, float* __restrict__ y)
{
    const int bidx = blockIdx.x;
    const float invZ = 1.0f / Z[bidx >> 10];
    const size_t i = ((size_t)bidx * 256 + threadIdx.x) * 4;
    const float4 a = *reinterpret_cast<const float4*>(&x[i]);
    const float4 b = *reinterpret_cast<const float4*>(&o[i]);
    float4 r{fmaf(b.x, invZ, a.x), fmaf(b.y, invZ, a.y),
             fmaf(b.z, invZ, a.z), fmaf(b.w, invZ, a.w)};
    *reinterpret_cast<float4*>(&y[i]) = r;
}

extern "C" void kernel_launch(void* const* d_in, const int* in_sizes, int n_in,
                              void* d_out, int out_size, void* d_ws, size_t ws_size,
                              hipStream_t stream)
{
    const float* x   = (const float*)d_in[0];
    const float* wt  = (const float*)d_in[1];
    const float* bt  = (const float*)d_in[2];
    const float* wc  = (const float*)d_in[3];
    const float* bc  = (const float*)d_in[4];
    const float* wbo = (const float*)d_in[5];
    const float* bbo = (const float*)d_in[6];
    const float* wo  = (const float*)d_in[7];
    const float* bo  = (const float*)d_in[8];
    float* out = (float*)d_out;

    uint8_t* w8 = (uint8_t*)d_ws;
    const size_t MB = 1u << 20;
    // [0,16): xtPh/xtPl/xcPh/xcPl (4 MB each)  -> later y[0,32)
    // [16,32): xbB bf16 [B][C][HW]             -> later y upper half
    // [32,48): xbP (dead after attn)           -> wbP2 overlays after attn
    // [48,80): O   (wbP1 overlays until conv-bottom done)
    short8* xtPh = (short8*)(w8);
    short8* xtPl = (short8*)(w8 + 4 * MB);
    short8* xcPh = (short8*)(w8 + 8 * MB);
    short8* xcPl = (short8*)(w8 + 12 * MB);
    __hip_bfloat16* xbB = (__hip_bfloat16*)(w8 + 16 * MB);
    short8* xbP  = (short8*)(w8 + 32 * MB);
    float*  O    = (float*)(w8 + 48 * MB);
    short8* Wb1  = (short8*)(w8 + 48 * MB);   // inside O region (dead before attn)
    short8* Wb2  = (short8*)(w8 + 32 * MB);   // inside xbP region (dead after attn)
    float*  y    = (float*)(w8);              // [0,32) after attn
    float*  Z    = (float*)(w8 + 80 * MB);

    hipMemsetAsync(Z, 0, B_ * sizeof(float), stream);
    k_prep_w<<<dim3(288), 256, 0, stream>>>(wbo, Wb1);
    k_conv1x1<<<dim3(16, 8, 8), 256, 0, stream>>>(x, wt, bt, wc, bc,
                                                  xtPh, xtPl, xcPh, xcPl);
    k_conv3x3_mfma<__hip_bfloat16><<<dim3(64, 2, 8), 256, 0, stream>>>(x, Wb1, bbo, xbB);
    k_pack_xb<<<dim3(4096), 256, 0, stream>>>(xbB, xbP);
    k_attn_mfma<<<dim3(64, 8), 256, 0, stream>>>(xtPh, xtPl, xcPh, xcPl, xbP, O, Z);
    k_prep_w<<<dim3(288), 256, 0, stream>>>(wo, Wb2);
    k_add<<<dim3(8192), 256, 0, stream>>>(x, O, Z, y);
    k_conv3x3_mfma<float><<<dim3(64, 2, 8), 256, 0, stream>>>(y, Wb2, bo, out);
}